// Round 5
// baseline (454.974 us; speedup 1.0000x reference)
//
#include <hip/hip_runtime.h>

// fixed-point scale for weighted-degree accumulation (2^25)
#define FIX 33554432.0f
#define FIXINV (1.0f / 33554432.0f)

typedef unsigned long long ull;

// ---------------- zero the 8 privatized degcnt copies ----------------
__global__ void zero_k(ull* degcnt8, long total) {
    long i = (long)blockIdx.x * blockDim.x + threadIdx.x;
    if (i < total) degcnt8[i] = 0ULL;
}

// ---------------- per-edge: packed 64-bit atomic into XCD-local copy ----------------
__global__ void count_deg_k(const int* __restrict__ dst, const float* __restrict__ ew,
                            ull* degcnt8, int n, int e) {
    int i = blockIdx.x * blockDim.x + threadIdx.x;
    ull* my = degcnt8 + (long)(blockIdx.x & 7) * n;  // blockIdx%8 ~ XCD id (round-robin)
    if (i < e) {
        unsigned fx = __float2uint_rn(ew[i] * FIX);
        atomicAdd(&my[dst[i]], (1ULL << 32) | (ull)fx);
    }
}

// ---------------- reduce 8 copies; add self-loop; emit dinv + cnt ----------------
__global__ void dinv_k(const ull* __restrict__ degcnt8, float* __restrict__ dinv,
                       int* __restrict__ cnt, int n) {
    int i = blockIdx.x * blockDim.x + threadIdx.x;
    if (i < n) {
        ull v = (ull)(1u << 25);  // self-loop weight 1.0 fixed-point
#pragma unroll
        for (int c = 0; c < 8; ++c) v += degcnt8[(long)c * n + i];
        cnt[i] = (int)(v >> 32);
        float d = (float)(unsigned)(v & 0xffffffffu) * FIXINV;  // >= 1.0 always
        dinv[i] = rsqrtf(d);
    }
}

// ---------------- scan step 1: per-2048-chunk exclusive scan ----------------
__global__ void scan1_k(const int* __restrict__ cnt, int* __restrict__ excl,
                        int* __restrict__ bsum, int n) {
    __shared__ int lds[256];
    int base = blockIdx.x * 2048;
    int pre[8];
    int tsum = 0;
#pragma unroll
    for (int j = 0; j < 8; ++j) {
        int idx = base + threadIdx.x * 8 + j;
        int v = (idx < n) ? cnt[idx] : 0;
        pre[j] = tsum;
        tsum += v;
    }
    lds[threadIdx.x] = tsum;
    __syncthreads();
    for (int off = 1; off < 256; off <<= 1) {
        int v = (threadIdx.x >= off) ? lds[threadIdx.x - off] : 0;
        __syncthreads();
        lds[threadIdx.x] += v;
        __syncthreads();
    }
    int texcl = lds[threadIdx.x] - tsum;
    if (threadIdx.x == 255) bsum[blockIdx.x] = lds[255];
#pragma unroll
    for (int j = 0; j < 8; ++j) {
        int idx = base + threadIdx.x * 8 + j;
        if (idx < n) excl[idx] = texcl + pre[j];
    }
}

// ---------------- scan step 2: serial exclusive scan of block sums ----------------
__global__ void scan2_k(int* bsum, int nb, int* rowptr_end, int e) {
    if (threadIdx.x == 0 && blockIdx.x == 0) {
        int run = 0;
        for (int i = 0; i < nb; ++i) {
            int v = bsum[i];
            bsum[i] = run;
            run += v;
        }
        *rowptr_end = e;
    }
}

// ---------------- scan step 3: add block offsets; produce rowptr + cursor ----------------
__global__ void scan3_k(int* __restrict__ rowptr, int* __restrict__ cursor,
                        const int* __restrict__ bsum, int n) {
    int i = blockIdx.x * blockDim.x + threadIdx.x;
    if (i < n) {
        int v = rowptr[i] + bsum[i >> 11];
        rowptr[i] = v;
        cursor[i] = v;
    }
}

// ---------------- CSR fill: ONE packed 8B store per edge ----------------
__global__ void fill_csr_k(const int* __restrict__ src, const int* __restrict__ dst,
                           const float* __restrict__ ew, const float* __restrict__ dinv,
                           int* cursor, ull* __restrict__ csr, int e) {
    int base = (blockIdx.x * blockDim.x + threadIdx.x) * 4;
    if (base + 3 < e) {
        int s[4], d[4], slot[4];
        ull rec[4];
#pragma unroll
        for (int j = 0; j < 4; ++j) { s[j] = src[base + j]; d[j] = dst[base + j]; }
#pragma unroll
        for (int j = 0; j < 4; ++j) {
            float wv = dinv[s[j]] * ew[base + j] * dinv[d[j]];
            rec[j] = ((ull)__float_as_uint(wv) << 32) | (unsigned)s[j];
        }
#pragma unroll
        for (int j = 0; j < 4; ++j) slot[j] = atomicAdd(&cursor[d[j]], 1);
#pragma unroll
        for (int j = 0; j < 4; ++j) csr[slot[j]] = rec[j];
    } else {
        for (int i = base; i < e; ++i) {
            int s = src[i], d = dst[i];
            int slot = atomicAdd(&cursor[d], 1);
            float wv = dinv[s] * ew[i] * dinv[d];
            csr[slot] = ((ull)__float_as_uint(wv) << 32) | (unsigned)s;
        }
    }
}

// ---------------- dense linear: y[n,C] = x[n,K] @ W[K,C], optional bias+ReLU ----------------
template <int K, int C, bool BIAS_RELU>
__global__ void linear_k(const float* __restrict__ x, const float* __restrict__ W,
                         const float* __restrict__ b, float* __restrict__ y, int n) {
    __shared__ float Ws[K * C];
    for (int i = threadIdx.x; i < K * C; i += blockDim.x) Ws[i] = W[i];
    __syncthreads();
    long gid = (long)blockIdx.x * blockDim.x + threadIdx.x;
    int node = (int)(gid / C);
    int c = (int)(gid % C);
    if (node >= n) return;
    const float* xr = x + (long)node * K;
    float acc = 0.0f;
#pragma unroll
    for (int k = 0; k < K; ++k) acc = fmaf(xr[k], Ws[k * C + c], acc);
    if (BIAS_RELU) acc = fmaxf(acc + b[c], 0.0f);
    y[(long)node * C + c] = acc;
}

// ---------------- gather at C=40: wave per node, lane = channel, packed CSR ----------------
template <bool ADD_BIAS>
__global__ void gather40_k(const int* __restrict__ rowptr, const ull* __restrict__ csr,
                           const float* __restrict__ feat, const float* __restrict__ dinv,
                           const float* __restrict__ b, float* __restrict__ out, int n) {
    int node = (int)(((long)blockIdx.x * blockDim.x + threadIdx.x) >> 6);
    int lane = threadIdx.x & 63;
    if (node >= n) return;
    int beg = __builtin_amdgcn_readfirstlane(rowptr[node]);
    int end = __builtin_amdgcn_readfirstlane(rowptr[node + 1]);
    if (lane >= 40) return;
    float di = dinv[node];
    float acc = di * di * feat[(long)node * 40 + lane];
    if (ADD_BIAS) acc += b[lane];
    int t = beg;
    for (; t + 3 < end; t += 4) {
        ull r0 = csr[t], r1 = csr[t + 1], r2 = csr[t + 2], r3 = csr[t + 3];
        float v0 = feat[(long)(unsigned)r0 * 40 + lane];
        float v1 = feat[(long)(unsigned)r1 * 40 + lane];
        float v2 = feat[(long)(unsigned)r2 * 40 + lane];
        float v3 = feat[(long)(unsigned)r3 * 40 + lane];
        acc = fmaf(__uint_as_float((unsigned)(r0 >> 32)), v0, acc);
        acc = fmaf(__uint_as_float((unsigned)(r1 >> 32)), v1, acc);
        acc = fmaf(__uint_as_float((unsigned)(r2 >> 32)), v2, acc);
        acc = fmaf(__uint_as_float((unsigned)(r3 >> 32)), v3, acc);
    }
    for (; t < end; ++t) {
        ull r = csr[t];
        acc = fmaf(__uint_as_float((unsigned)(r >> 32)), feat[(long)(unsigned)r * 40 + lane], acc);
    }
    out[(long)node * 40 + lane] = acc;
}

extern "C" void kernel_launch(void* const* d_in, const int* in_sizes, int n_in,
                              void* d_out, int out_size, void* d_ws, size_t ws_size,
                              hipStream_t stream) {
    const float* x = (const float*)d_in[0];
    const int* ei = (const int*)d_in[1];
    const float* ew = (const float*)d_in[2];
    const float* W1 = (const float*)d_in[3];
    const float* b1 = (const float*)d_in[4];
    const float* W2 = (const float*)d_in[5];
    const float* b2 = (const float*)d_in[6];
    float* out = (float*)d_out;

    const int n = in_sizes[0] / 40;   // 100000
    const int e = in_sizes[2];        // 1600000
    const int* srcp = ei;
    const int* dstp = ei + e;

    // ws layout (4B units):
    // csr[e] (8B recs) | dinv[n] | cnt[n] | rowptr[n+1] | bsum[64] | agg1/xl2[n*40] | h[n*64]
    // degcnt8 (8 copies, 8B) overlays h's region (dead until linear1).
    ull* csr = (ull*)d_ws;
    float* dinv = (float*)(csr + e);
    int* cnt = (int*)(dinv + n);          // reused as cursor
    int* rowptr = cnt + n;
    int* bsum = rowptr + n + 1;
    float* agg1 = (float*)(bsum + 64);    // layer-1 aggregated x [n,40]
    float* h = agg1 + (long)n * 40;       // hidden [n,64]
    float* xl2 = agg1;                    // overlay: agg1 dead after linear1
    ull* degcnt8 = (ull*)(((unsigned long long)(uintptr_t)h + 7) & ~7ULL);

    const int B = 256;
    auto cdiv = [](long a, long b) { return (int)((a + b - 1) / b); };
    const int nb = cdiv(n, 2048);

    // ---- CSR build (shared by both layers) ----
    zero_k<<<cdiv((long)n * 8, B), B, 0, stream>>>(degcnt8, (long)n * 8);
    count_deg_k<<<cdiv(e, B), B, 0, stream>>>(dstp, ew, degcnt8, n, e);
    dinv_k<<<cdiv(n, B), B, 0, stream>>>(degcnt8, dinv, cnt, n);
    scan1_k<<<nb, 256, 0, stream>>>(cnt, rowptr, bsum, n);
    scan2_k<<<1, 64, 0, stream>>>(bsum, nb, rowptr + n, e);
    scan3_k<<<cdiv(n, B), B, 0, stream>>>(rowptr, cnt, bsum, n);
    fill_csr_k<<<cdiv(e, (long)B * 4), B, 0, stream>>>(srcp, dstp, ew, dinv, cnt, csr, e);

    // ---- layer 1: agg1 = A_norm @ x (C=40), then h = relu(agg1 @ W1 + b1) ----
    gather40_k<false><<<cdiv((long)n * 64, B), B, 0, stream>>>(rowptr, csr, x, dinv, nullptr, agg1, n);
    linear_k<40, 64, true><<<cdiv((long)n * 64, B), B, 0, stream>>>(agg1, W1, b1, h, n);

    // ---- layer 2: xl2 = h @ W2 (C=40), then out = A_norm @ xl2 + b2 ----
    linear_k<64, 40, false><<<cdiv((long)n * 40, B), B, 0, stream>>>(h, W2, nullptr, xl2, n);
    gather40_k<true><<<cdiv((long)n * 64, B), B, 0, stream>>>(rowptr, csr, xl2, dinv, b2, out, n);
}

// Round 6
// 431.261 us; speedup vs baseline: 1.0550x; 1.0550x over previous
//
#include <hip/hip_runtime.h>
#include <hip/hip_fp16.h>

// fixed-point scale for weighted-degree accumulation (2^25)
#define FIX 33554432.0f
#define FIXINV (1.0f / 33554432.0f)

typedef unsigned long long ull;

// ---------------- zero the 8 privatized degcnt copies ----------------
__global__ void zero_k(ull* degcnt8, long total) {
    long i = (long)blockIdx.x * blockDim.x + threadIdx.x;
    if (i < total) degcnt8[i] = 0ULL;
}

// ---------------- per-edge: packed 64-bit atomic into XCD-local copy ----------------
__global__ void count_deg_k(const int* __restrict__ dst, const float* __restrict__ ew,
                            ull* degcnt8, int n, int e) {
    int i = blockIdx.x * blockDim.x + threadIdx.x;
    ull* my = degcnt8 + (long)(blockIdx.x & 7) * n;  // blockIdx%8 ~ XCD id (round-robin)
    if (i < e) {
        unsigned fx = __float2uint_rn(ew[i] * FIX);
        atomicAdd(&my[dst[i]], (1ULL << 32) | (ull)fx);
    }
}

// ---------------- reduce 8 copies; add self-loop; emit dinv + cnt ----------------
__global__ void dinv_k(const ull* __restrict__ degcnt8, float* __restrict__ dinv,
                       int* __restrict__ cnt, int n) {
    int i = blockIdx.x * blockDim.x + threadIdx.x;
    if (i < n) {
        ull v = (ull)(1u << 25);  // self-loop weight 1.0 fixed-point
#pragma unroll
        for (int c = 0; c < 8; ++c) v += degcnt8[(long)c * n + i];
        cnt[i] = (int)(v >> 32);
        float d = (float)(unsigned)(v & 0xffffffffu) * FIXINV;  // >= 1.0 always
        dinv[i] = rsqrtf(d);
    }
}

// ---------------- scan step 1: per-2048-chunk exclusive scan ----------------
__global__ void scan1_k(const int* __restrict__ cnt, int* __restrict__ excl,
                        int* __restrict__ bsum, int n) {
    __shared__ int lds[256];
    int base = blockIdx.x * 2048;
    int pre[8];
    int tsum = 0;
#pragma unroll
    for (int j = 0; j < 8; ++j) {
        int idx = base + threadIdx.x * 8 + j;
        int v = (idx < n) ? cnt[idx] : 0;
        pre[j] = tsum;
        tsum += v;
    }
    lds[threadIdx.x] = tsum;
    __syncthreads();
    for (int off = 1; off < 256; off <<= 1) {
        int v = (threadIdx.x >= off) ? lds[threadIdx.x - off] : 0;
        __syncthreads();
        lds[threadIdx.x] += v;
        __syncthreads();
    }
    int texcl = lds[threadIdx.x] - tsum;
    if (threadIdx.x == 255) bsum[blockIdx.x] = lds[255];
#pragma unroll
    for (int j = 0; j < 8; ++j) {
        int idx = base + threadIdx.x * 8 + j;
        if (idx < n) excl[idx] = texcl + pre[j];
    }
}

// ---------------- scan step 2: serial exclusive scan of block sums ----------------
__global__ void scan2_k(int* bsum, int nb, int* rowptr_end, int e) {
    if (threadIdx.x == 0 && blockIdx.x == 0) {
        int run = 0;
        for (int i = 0; i < nb; ++i) {
            int v = bsum[i];
            bsum[i] = run;
            run += v;
        }
        *rowptr_end = e;
    }
}

// ---------------- scan step 3: add block offsets; produce rowptr + cursor ----------------
__global__ void scan3_k(int* __restrict__ rowptr, int* __restrict__ cursor,
                        const int* __restrict__ bsum, int n) {
    int i = blockIdx.x * blockDim.x + threadIdx.x;
    if (i < n) {
        int v = rowptr[i] + bsum[i >> 11];
        rowptr[i] = v;
        cursor[i] = v;
    }
}

// ---------------- CSR fill: two-array (col,w), w' = ew*dinv[src] only ----------------
__global__ void fill_csr_k(const int* __restrict__ src, const int* __restrict__ dst,
                           const float* __restrict__ ew, const float* __restrict__ dinv,
                           int* cursor, int* __restrict__ col, float* __restrict__ w, int e) {
    int base = (blockIdx.x * blockDim.x + threadIdx.x) * 4;
    if (base + 3 < e) {
        int4 s4 = *reinterpret_cast<const int4*>(src + base);
        int4 d4 = *reinterpret_cast<const int4*>(dst + base);
        float4 e4 = *reinterpret_cast<const float4*>(ew + base);
        int s[4] = {s4.x, s4.y, s4.z, s4.w};
        int d[4] = {d4.x, d4.y, d4.z, d4.w};
        float ev[4] = {e4.x, e4.y, e4.z, e4.w};
        float wv[4];
        int slot[4];
#pragma unroll
        for (int j = 0; j < 4; ++j) wv[j] = dinv[s[j]] * ev[j];
#pragma unroll
        for (int j = 0; j < 4; ++j) slot[j] = atomicAdd(&cursor[d[j]], 1);
#pragma unroll
        for (int j = 0; j < 4; ++j) { col[slot[j]] = s[j]; w[slot[j]] = wv[j]; }
    } else {
        for (int i = base; i < e; ++i) {
            int s = src[i], d = dst[i];
            int slot = atomicAdd(&cursor[d], 1);
            col[slot] = s;
            w[slot] = dinv[s] * ew[i];
        }
    }
}

// ---------------- f32 -> fp16 convert (vectorized) ----------------
__global__ void tohalf_k(const float4* __restrict__ in, __half2* __restrict__ out, long n4) {
    long i = (long)blockIdx.x * blockDim.x + threadIdx.x;
    if (i < n4) {
        float4 v = in[i];
        out[2 * i] = __floats2half2_rn(v.x, v.y);
        out[2 * i + 1] = __floats2half2_rn(v.z, v.w);
    }
}

// ---------------- dense linear: y[n,C] = x[n,K] @ W[K,C] ----------------
// BIAS_RELU: +b then relu. DUAL16: also emit fp16 copy.
template <int K, int C, bool BIAS_RELU, bool DUAL16>
__global__ void linear_k(const float* __restrict__ x, const float* __restrict__ W,
                         const float* __restrict__ b, float* __restrict__ y,
                         __half* __restrict__ y16, int n) {
    __shared__ float Ws[K * C];
    for (int i = threadIdx.x; i < K * C; i += blockDim.x) Ws[i] = W[i];
    __syncthreads();
    long gid = (long)blockIdx.x * blockDim.x + threadIdx.x;
    int node = (int)(gid / C);
    int c = (int)(gid % C);
    if (node >= n) return;
    const float* xr = x + (long)node * K;
    float acc = 0.0f;
#pragma unroll
    for (int k = 0; k < K; ++k) acc = fmaf(xr[k], Ws[k * C + c], acc);
    if (BIAS_RELU) acc = fmaxf(acc + b[c], 0.0f);
    y[gid] = acc;
    if (DUAL16) y16[gid] = __float2half(acc);
}

// ---------------- gather at C=40: wave/node, lane=channel, fp16 edge operand ----------------
// out = dinv[d] * sum(w' * feat16[src]) + dinv[d]^2 * selfF[d] (+ b)
template <bool ADD_BIAS>
__global__ void gather40_k(const int* __restrict__ rowptr, const int* __restrict__ col,
                           const float* __restrict__ w, const __half* __restrict__ feat16,
                           const float* __restrict__ selfF, const float* __restrict__ dinv,
                           const float* __restrict__ b, float* __restrict__ out, int n) {
    int node = (int)(((long)blockIdx.x * blockDim.x + threadIdx.x) >> 6);
    int lane = threadIdx.x & 63;
    if (node >= n) return;
    int beg = __builtin_amdgcn_readfirstlane(rowptr[node]);
    int end = __builtin_amdgcn_readfirstlane(rowptr[node + 1]);
    if (lane >= 40) return;
    float accE = 0.0f;
    int t = beg;
    for (; t + 3 < end; t += 4) {
        int s0 = col[t], s1 = col[t + 1], s2 = col[t + 2], s3 = col[t + 3];
        float w0 = w[t], w1 = w[t + 1], w2 = w[t + 2], w3 = w[t + 3];
        float v0 = __half2float(feat16[(long)s0 * 40 + lane]);
        float v1 = __half2float(feat16[(long)s1 * 40 + lane]);
        float v2 = __half2float(feat16[(long)s2 * 40 + lane]);
        float v3 = __half2float(feat16[(long)s3 * 40 + lane]);
        accE = fmaf(w0, v0, accE);
        accE = fmaf(w1, v1, accE);
        accE = fmaf(w2, v2, accE);
        accE = fmaf(w3, v3, accE);
    }
    for (; t < end; ++t)
        accE = fmaf(w[t], __half2float(feat16[(long)col[t] * 40 + lane]), accE);
    float di = dinv[node];
    float r = di * accE + di * di * selfF[(long)node * 40 + lane];
    if (ADD_BIAS) r += b[lane];
    out[(long)node * 40 + lane] = r;
}

extern "C" void kernel_launch(void* const* d_in, const int* in_sizes, int n_in,
                              void* d_out, int out_size, void* d_ws, size_t ws_size,
                              hipStream_t stream) {
    const float* x = (const float*)d_in[0];
    const int* ei = (const int*)d_in[1];
    const float* ew = (const float*)d_in[2];
    const float* W1 = (const float*)d_in[3];
    const float* b1 = (const float*)d_in[4];
    const float* W2 = (const float*)d_in[5];
    const float* b2 = (const float*)d_in[6];
    float* out = (float*)d_out;

    const int n = in_sizes[0] / 40;   // 100000
    const int e = in_sizes[2];        // 1600000
    const int* srcp = ei;
    const int* dstp = ei + e;

    // ws layout (4B units):
    // col[e] | wcsr[e] | dinv[n] | cnt[n] | rowptr[n+1] | bsum[64] |
    // agg1/xl2_32[n*40] | h[n*64] | xl2_16[n*20]
    // overlays inside h's region (both dead before linear1 writes h):
    //   x16 (n*20 floats worth of halves) at h, degcnt8 (n*16 floats) after it
    int* col = (int*)d_ws;
    float* wcsr = (float*)(col + e);
    float* dinv = wcsr + e;
    int* cnt = (int*)(dinv + n);          // reused as cursor
    int* rowptr = cnt + n;
    int* bsum = rowptr + n + 1;
    float* agg1 = (float*)(bsum + 64);    // layer-1 aggregated x [n,40] f32
    float* h = agg1 + (long)n * 40;       // hidden [n,64] f32
    float* xl2_32 = agg1;                 // overlay: agg1 dead after linear1
    __half* xl2_16 = (__half*)(h + (long)n * 64);
    __half* x16 = (__half*)h;             // overlay in h region
    ull* degcnt8 = (ull*)(((uintptr_t)(h + (long)n * 20) + 7) & ~(uintptr_t)7);

    const int B = 256;
    auto cdiv = [](long a, long b) { return (int)((a + b - 1) / b); };
    const int nb = cdiv(n, 2048);

    // ---- CSR build (shared by both layers) ----
    zero_k<<<cdiv((long)n * 8, B), B, 0, stream>>>(degcnt8, (long)n * 8);
    count_deg_k<<<cdiv(e, B), B, 0, stream>>>(dstp, ew, degcnt8, n, e);
    dinv_k<<<cdiv(n, B), B, 0, stream>>>(degcnt8, dinv, cnt, n);
    scan1_k<<<nb, 256, 0, stream>>>(cnt, rowptr, bsum, n);
    scan2_k<<<1, 64, 0, stream>>>(bsum, nb, rowptr + n, e);
    scan3_k<<<cdiv(n, B), B, 0, stream>>>(rowptr, cnt, bsum, n);
    fill_csr_k<<<cdiv(e, (long)B * 4), B, 0, stream>>>(srcp, dstp, ew, dinv, cnt, col, wcsr, e);

    // ---- x -> fp16 (edge-gather operand for layer 1) ----
    tohalf_k<<<cdiv((long)n * 10, B), B, 0, stream>>>((const float4*)x, (__half2*)x16, (long)n * 10);

    // ---- layer 1: agg1 = A_norm @ x, then h = relu(agg1 @ W1 + b1) ----
    gather40_k<false><<<cdiv((long)n * 64, B), B, 0, stream>>>(rowptr, col, wcsr, x16, x, dinv, nullptr, agg1, n);
    linear_k<40, 64, true, false><<<cdiv((long)n * 64, B), B, 0, stream>>>(agg1, W1, b1, h, nullptr, n);

    // ---- layer 2: xl2 = h @ W2 (f32 + fp16), then out = A_norm @ xl2 + b2 ----
    linear_k<64, 40, false, true><<<cdiv((long)n * 40, B), B, 0, stream>>>(h, W2, nullptr, xl2_32, xl2_16, n);
    gather40_k<true><<<cdiv((long)n * 64, B), B, 0, stream>>>(rowptr, col, wcsr, xl2_16, xl2_32, dinv, b2, out, n);
}

// Round 7
// 416.650 us; speedup vs baseline: 1.0920x; 1.0351x over previous
//
#include <hip/hip_runtime.h>
#include <hip/hip_fp16.h>

// fixed-point scale for weighted-degree accumulation (2^25)
#define FIX 33554432.0f
#define FIXINV (1.0f / 33554432.0f)

typedef unsigned long long ull;

// edges per block for edge-walk kernels (count_deg_k and part1_k MUST match:
// identical grid shape + blockIdx&7 class => per-(bucket,class) counts line up)
#define EB 1024

// ---------------- zero the 8 privatized degcnt copies ----------------
__global__ void zero_k(ull* degcnt8, long total) {
    long i = (long)blockIdx.x * blockDim.x + threadIdx.x;
    if (i < total) degcnt8[i] = 0ULL;
}

// ---------------- per-edge: packed 64-bit atomic into XCD-class-local copy ----------------
__global__ void count_deg_k(const int* __restrict__ dst, const float* __restrict__ ew,
                            ull* degcnt8, int n, int e) {
    ull* my = degcnt8 + (long)(blockIdx.x & 7) * n;
    int base = blockIdx.x * EB + threadIdx.x * 4;
    if (base + 3 < e) {
        int4 d4 = *reinterpret_cast<const int4*>(dst + base);
        float4 e4 = *reinterpret_cast<const float4*>(ew + base);
        atomicAdd(&my[d4.x], (1ULL << 32) | (ull)__float2uint_rn(e4.x * FIX));
        atomicAdd(&my[d4.y], (1ULL << 32) | (ull)__float2uint_rn(e4.y * FIX));
        atomicAdd(&my[d4.z], (1ULL << 32) | (ull)__float2uint_rn(e4.z * FIX));
        atomicAdd(&my[d4.w], (1ULL << 32) | (ull)__float2uint_rn(e4.w * FIX));
    } else {
        for (int i = base; i < e && i < base + 4; ++i)
            atomicAdd(&my[dst[i]], (1ULL << 32) | (ull)__float2uint_rn(ew[i] * FIX));
    }
}

// ---------------- reduce 8 copies; add self-loop; emit dinv + cnt ----------------
__global__ void dinv_k(const ull* __restrict__ degcnt8, float* __restrict__ dinv,
                       int* __restrict__ cnt, int n) {
    int i = blockIdx.x * blockDim.x + threadIdx.x;
    if (i < n) {
        ull v = (ull)(1u << 25);  // self-loop weight 1.0 fixed-point
#pragma unroll
        for (int c = 0; c < 8; ++c) v += degcnt8[(long)c * n + i];
        cnt[i] = (int)(v >> 32);
        float d = (float)(unsigned)(v & 0xffffffffu) * FIXINV;  // >= 1.0 always
        dinv[i] = rsqrtf(d);
    }
}

// ---------------- scan step 1: per-2048-chunk exclusive scan ----------------
__global__ void scan1_k(const int* __restrict__ cnt, int* __restrict__ excl,
                        int* __restrict__ bsum, int n) {
    __shared__ int lds[256];
    int base = blockIdx.x * 2048;
    int pre[8];
    int tsum = 0;
#pragma unroll
    for (int j = 0; j < 8; ++j) {
        int idx = base + threadIdx.x * 8 + j;
        int v = (idx < n) ? cnt[idx] : 0;
        pre[j] = tsum;
        tsum += v;
    }
    lds[threadIdx.x] = tsum;
    __syncthreads();
    for (int off = 1; off < 256; off <<= 1) {
        int v = (threadIdx.x >= off) ? lds[threadIdx.x - off] : 0;
        __syncthreads();
        lds[threadIdx.x] += v;
        __syncthreads();
    }
    int texcl = lds[threadIdx.x] - tsum;
    if (threadIdx.x == 255) bsum[blockIdx.x] = lds[255];
#pragma unroll
    for (int j = 0; j < 8; ++j) {
        int idx = base + threadIdx.x * 8 + j;
        if (idx < n) excl[idx] = texcl + pre[j];
    }
}

// ---------------- scan step 2: serial exclusive scan of block sums ----------------
__global__ void scan2_k(int* bsum, int nb, int* rowptr_end, int e) {
    if (threadIdx.x == 0 && blockIdx.x == 0) {
        int run = 0;
        for (int i = 0; i < nb; ++i) {
            int v = bsum[i];
            bsum[i] = run;
            run += v;
        }
        *rowptr_end = e;
    }
}

// ---------------- scan step 3: add block offsets -> final rowptr ----------------
__global__ void scan3_k(int* __restrict__ rowptr, const int* __restrict__ bsum, int n) {
    int i = blockIdx.x * blockDim.x + threadIdx.x;
    if (i < n) rowptr[i] += bsum[i >> 11];
}

// ---------------- per-(bucket,class) cursor bases from privatized counts ----------------
// bucket = 256 dst nodes. bxcur[(b*8+x)*16] = rowptr[256b] + sum_{x'<x} cnt(b,x')
__global__ void bxcur_k(const ull* __restrict__ degcnt8, const int* __restrict__ rowptr,
                        int* __restrict__ bxcur, int n) {
    __shared__ int lds[256];
    __shared__ int xs[8];
    int b = blockIdx.x;
    int node = b * 256 + threadIdx.x;
#pragma unroll
    for (int x = 0; x < 8; ++x) {
        lds[threadIdx.x] = (node < n) ? (int)(degcnt8[(long)x * n + node] >> 32) : 0;
        __syncthreads();
        for (int off = 128; off > 0; off >>= 1) {
            if (threadIdx.x < off) lds[threadIdx.x] += lds[threadIdx.x + off];
            __syncthreads();
        }
        if (threadIdx.x == 0) xs[x] = lds[0];
        __syncthreads();
    }
    if (threadIdx.x == 0) {
        int run = rowptr[b * 256];
#pragma unroll
        for (int x = 0; x < 8; ++x) {
            bxcur[(b * 8 + x) * 16] = run;  // 64B-padded cursor
            run += xs[x];
        }
    }
}

// ---------------- phase 1: bucket-partition edges, packed 8B records ----------------
// rec = wbits[59:28] | src[27:8] | (dst&255)[7:0]   (src < 2^20)
__global__ void part1_k(const int* __restrict__ src, const int* __restrict__ dst,
                        const float* __restrict__ ew, const float* __restrict__ dinv,
                        int* bxcur, ull* __restrict__ tmp, int e) {
    int x = blockIdx.x & 7;
    int base = blockIdx.x * EB + threadIdx.x * 4;
    if (base + 3 < e) {
        int4 s4 = *reinterpret_cast<const int4*>(src + base);
        int4 d4 = *reinterpret_cast<const int4*>(dst + base);
        float4 e4 = *reinterpret_cast<const float4*>(ew + base);
        int s[4] = {s4.x, s4.y, s4.z, s4.w};
        int d[4] = {d4.x, d4.y, d4.z, d4.w};
        float ev[4] = {e4.x, e4.y, e4.z, e4.w};
        ull rec[4];
        int slot[4];
#pragma unroll
        for (int j = 0; j < 4; ++j) {
            float wv = dinv[s[j]] * ev[j];
            rec[j] = ((ull)__float_as_uint(wv) << 28) | ((ull)(unsigned)s[j] << 8) |
                     (ull)(unsigned)(d[j] & 255);
        }
#pragma unroll
        for (int j = 0; j < 4; ++j) slot[j] = atomicAdd(&bxcur[((d[j] >> 8) * 8 + x) * 16], 1);
#pragma unroll
        for (int j = 0; j < 4; ++j) tmp[slot[j]] = rec[j];
    } else {
        for (int i = base; i < e && i < base + 4; ++i) {
            int s = src[i], d = dst[i];
            float wv = dinv[s] * ew[i];
            int slot = atomicAdd(&bxcur[((d >> 8) * 8 + x) * 16], 1);
            tmp[slot] = ((ull)__float_as_uint(wv) << 28) | ((ull)(unsigned)s << 8) |
                        (ull)(unsigned)(d & 255);
        }
    }
}

// ---------------- phase 2: within-bucket counting sort -> final CSR (L2-local stores) ----------------
__global__ void part2_k(const ull* __restrict__ tmp, const int* __restrict__ rowptr,
                        int* __restrict__ col, float* __restrict__ w, int n, int e) {
    __shared__ int lcur[256];
    int b = blockIdx.x;
    int nlo = b * 256;
    int node = nlo + threadIdx.x;
    lcur[threadIdx.x] = (node < n) ? rowptr[node] : 0;
    __syncthreads();
    int beg = rowptr[nlo];
    int hi = nlo + 256;
    int end = rowptr[hi < n ? hi : n];
    for (int i = beg + threadIdx.x; i < end; i += 256) {
        ull rec = tmp[i];
        int dlo = (int)(rec & 255);
        int s = (int)((rec >> 8) & 0xFFFFF);
        unsigned wb = (unsigned)(rec >> 28);
        int slot = atomicAdd(&lcur[dlo], 1);
        col[slot] = s;
        w[slot] = __uint_as_float(wb);
    }
}

// ---------------- f32 -> fp16 convert (vectorized) ----------------
__global__ void tohalf_k(const float4* __restrict__ in, __half2* __restrict__ out, long n4) {
    long i = (long)blockIdx.x * blockDim.x + threadIdx.x;
    if (i < n4) {
        float4 v = in[i];
        out[2 * i] = __floats2half2_rn(v.x, v.y);
        out[2 * i + 1] = __floats2half2_rn(v.z, v.w);
    }
}

// ---------------- dense linear: y[n,C] = x[n,K] @ W[K,C] ----------------
template <int K, int C, bool BIAS_RELU, bool DUAL16>
__global__ void linear_k(const float* __restrict__ x, const float* __restrict__ W,
                         const float* __restrict__ b, float* __restrict__ y,
                         __half* __restrict__ y16, int n) {
    __shared__ float Ws[K * C];
    for (int i = threadIdx.x; i < K * C; i += blockDim.x) Ws[i] = W[i];
    __syncthreads();
    long gid = (long)blockIdx.x * blockDim.x + threadIdx.x;
    int node = (int)(gid / C);
    int c = (int)(gid % C);
    if (node >= n) return;
    const float* xr = x + (long)node * K;
    float acc = 0.0f;
#pragma unroll
    for (int k = 0; k < K; ++k) acc = fmaf(xr[k], Ws[k * C + c], acc);
    if (BIAS_RELU) acc = fmaxf(acc + b[c], 0.0f);
    y[gid] = acc;
    if (DUAL16) y16[gid] = __float2half(acc);
}

// ---------------- gather at C=40: wave/node, lane=channel, fp16 edge operand ----------------
// out = dinv[d] * sum(w' * feat16[src]) + dinv[d]^2 * selfF[d] (+ b)
template <bool ADD_BIAS>
__global__ void gather40_k(const int* __restrict__ rowptr, const int* __restrict__ col,
                           const float* __restrict__ w, const __half* __restrict__ feat16,
                           const float* __restrict__ selfF, const float* __restrict__ dinv,
                           const float* __restrict__ b, float* __restrict__ out, int n) {
    int node = (int)(((long)blockIdx.x * blockDim.x + threadIdx.x) >> 6);
    int lane = threadIdx.x & 63;
    if (node >= n) return;
    int beg = __builtin_amdgcn_readfirstlane(rowptr[node]);
    int end = __builtin_amdgcn_readfirstlane(rowptr[node + 1]);
    if (lane >= 40) return;
    float accE = 0.0f;
    int t = beg;
    for (; t + 3 < end; t += 4) {
        int s0 = col[t], s1 = col[t + 1], s2 = col[t + 2], s3 = col[t + 3];
        float w0 = w[t], w1 = w[t + 1], w2 = w[t + 2], w3 = w[t + 3];
        float v0 = __half2float(feat16[(long)s0 * 40 + lane]);
        float v1 = __half2float(feat16[(long)s1 * 40 + lane]);
        float v2 = __half2float(feat16[(long)s2 * 40 + lane]);
        float v3 = __half2float(feat16[(long)s3 * 40 + lane]);
        accE = fmaf(w0, v0, accE);
        accE = fmaf(w1, v1, accE);
        accE = fmaf(w2, v2, accE);
        accE = fmaf(w3, v3, accE);
    }
    for (; t < end; ++t)
        accE = fmaf(w[t], __half2float(feat16[(long)col[t] * 40 + lane]), accE);
    float di = dinv[node];
    float r = di * accE + di * di * selfF[(long)node * 40 + lane];
    if (ADD_BIAS) r += b[lane];
    out[(long)node * 40 + lane] = r;
}

extern "C" void kernel_launch(void* const* d_in, const int* in_sizes, int n_in,
                              void* d_out, int out_size, void* d_ws, size_t ws_size,
                              hipStream_t stream) {
    const float* x = (const float*)d_in[0];
    const int* ei = (const int*)d_in[1];
    const float* ew = (const float*)d_in[2];
    const float* W1 = (const float*)d_in[3];
    const float* b1 = (const float*)d_in[4];
    const float* W2 = (const float*)d_in[5];
    const float* b2 = (const float*)d_in[6];
    float* out = (float*)d_out;

    const int n = in_sizes[0] / 40;   // 100000
    const int e = in_sizes[2];        // 1600000
    const int* srcp = ei;
    const int* dstp = ei + e;
    const int NB = (n + 255) >> 8;    // buckets of 256 dst nodes

    // ws layout (4B units):
    // col[e] | wcsr[e] | dinv[n] | cnt[n] | rowptr[n+1] | bsum[64] | bxcur[NB*128] |
    // agg1/xl2_32[n*40] | h[n*64] | xl2_16 (n*40 halves)
    // overlays in h region (all dead before linear1 writes h):
    //   degcnt8 (8n ull) at h; tmp (e ull) after degcnt8; x16 (40n halves) at h after tmp dead
    int* col = (int*)d_ws;
    float* wcsr = (float*)(col + e);
    float* dinv = wcsr + e;
    int* cnt = (int*)(dinv + n);
    int* rowptr = cnt + n;
    int* bsum = rowptr + n + 1;
    int* bxcur = bsum + 64;
    float* agg1 = (float*)(bxcur + NB * 128);
    float* h = agg1 + (long)n * 40;
    float* xl2_32 = agg1;
    __half* xl2_16 = (__half*)(h + (long)n * 64);
    ull* degcnt8 = (ull*)(((uintptr_t)h + 7) & ~(uintptr_t)7);
    ull* tmp = degcnt8 + (long)n * 8;
    __half* x16 = (__half*)h;

    const int B = 256;
    auto cdiv = [](long a, long b) { return (int)((a + b - 1) / b); };
    const int nb = cdiv(n, 2048);
    const int egrid = cdiv(e, EB);  // shared by count_deg_k / part1_k (class match!)

    // ---- CSR build (shared by both layers) ----
    zero_k<<<cdiv((long)n * 8, B), B, 0, stream>>>(degcnt8, (long)n * 8);
    count_deg_k<<<egrid, B, 0, stream>>>(dstp, ew, degcnt8, n, e);
    dinv_k<<<cdiv(n, B), B, 0, stream>>>(degcnt8, dinv, cnt, n);
    scan1_k<<<nb, 256, 0, stream>>>(cnt, rowptr, bsum, n);
    scan2_k<<<1, 64, 0, stream>>>(bsum, nb, rowptr + n, e);
    scan3_k<<<cdiv(n, B), B, 0, stream>>>(rowptr, bsum, n);
    bxcur_k<<<NB, 256, 0, stream>>>(degcnt8, rowptr, bxcur, n);
    part1_k<<<egrid, B, 0, stream>>>(srcp, dstp, ew, dinv, bxcur, tmp, e);
    part2_k<<<NB, 256, 0, stream>>>(tmp, rowptr, col, wcsr, n, e);

    // ---- x -> fp16 (edge-gather operand for layer 1) ----
    tohalf_k<<<cdiv((long)n * 10, B), B, 0, stream>>>((const float4*)x, (__half2*)x16, (long)n * 10);

    // ---- layer 1: agg1 = A_norm @ x, then h = relu(agg1 @ W1 + b1) ----
    gather40_k<false><<<cdiv((long)n * 64, B), B, 0, stream>>>(rowptr, col, wcsr, x16, x, dinv, nullptr, agg1, n);
    linear_k<40, 64, true, false><<<cdiv((long)n * 64, B), B, 0, stream>>>(agg1, W1, b1, h, nullptr, n);

    // ---- layer 2: xl2 = h @ W2 (f32 + fp16), then out = A_norm @ xl2 + b2 ----
    linear_k<64, 40, false, true><<<cdiv((long)n * 40, B), B, 0, stream>>>(h, W2, nullptr, xl2_32, xl2_16, n);
    gather40_k<true><<<cdiv((long)n * 64, B), B, 0, stream>>>(rowptr, col, wcsr, xl2_16, xl2_32, dinv, b2, out, n);
}